// Round 2
// baseline (117.570 us; speedup 1.0000x reference)
//
#include <hip/hip_runtime.h>
#include <hip/hip_bf16.h>

// Problem constants (fixed by the reference):
constexpr int NB = 256;   // batch
constexpr int SQ = 512;   // sequence length
constexpr int ED = 512;   // encoder dim
constexpr int DD = 512;   // decoder dim
constexpr int UU = 64;    // attention units

typedef __attribute__((ext_vector_type(8))) short bf16x8;
typedef __attribute__((ext_vector_type(4))) short bf16x4;
typedef __attribute__((ext_vector_type(4))) float f32x4;

__device__ __forceinline__ unsigned short bf16_rne(float f) {
  unsigned int u = __float_as_uint(f);
  u += 0x7FFFu + ((u >> 16) & 1u);
  return (unsigned short)(u >> 16);
}

// ---------------------------------------------------------------------------
// Kernel 0: split w2 (512x64 fp32) into hi/lo bf16, pre-arranged in MFMA
// B-fragment order for mfma_f32_16x16x32_bf16:
//   B[k][col]: lane l holds k = (l>>4)*8 + j (j=0..7), col = l&15.
// ws layout (ushort): [ks 0..15][hl 0..1][nt 0..3][lane 0..63][j 0..7]
//   -> per k-step a contiguous 8192-byte block, staged to LDS linearly.
// ---------------------------------------------------------------------------
__global__ void prep_w2_frags(const float* __restrict__ w2,
                              unsigned short* __restrict__ wsb) {
  int tid = blockIdx.x * 256 + threadIdx.x;   // 0..65535
  int j    = tid & 7;
  int lane = (tid >> 3) & 63;
  int nt   = (tid >> 9) & 3;
  int hl   = (tid >> 11) & 1;
  int ks   = tid >> 12;
  int e = ks * 32 + (lane >> 4) * 8 + j;
  int u = nt * 16 + (lane & 15);
  float v = w2[e * UU + u];
  unsigned short hi = bf16_rne(v);
  unsigned short o;
  if (hl == 0) {
    o = hi;
  } else {
    float hif = __uint_as_float((unsigned int)hi << 16);
    o = bf16_rne(v - hif);   // residual, captures next ~8 mantissa bits
  }
  wsb[tid] = o;
}

// ---------------------------------------------------------------------------
// Kernel 1: fused attention. One block per batch element, 1024 threads
// (16 waves = 4/SIMD; round-1's 512-thread version sat at 23% occupancy and
// was latency-bound: MfmaUtil 5.9%, VALUBusy 17%).
// Wave w owns s-rows [w*32, w*32+32) x all 64 u in the projection GEMM.
// Proj GEMM via split-bf16 MFMA (3 mfma per tile: hi*hi + hi*lo + lo*hi).
// Then scores -> block softmax -> context accumulation (8 s-subsets x
// 128 e-chunks, float4 loads, LDS partial reduce).
// ---------------------------------------------------------------------------
__global__ __launch_bounds__(1024, 4) void attn_fused(
    const float* __restrict__ dh,    // [256,512] decoder hidden
    const float* __restrict__ x,     // [256,512,512] encoder output
    const float* __restrict__ w1,    // [512,64]
    const float* __restrict__ w1b,   // [64]
    const float* __restrict__ w2b,   // [64]
    const float* __restrict__ vk,    // [64]
    const unsigned short* __restrict__ wsb,  // w2 fragments (hi/lo)
    float* __restrict__ out)         // [256*512 ctx][256*512 att]
{
  const int b = blockIdx.x;
  const int t = threadIdx.x;
  const int wave = t >> 6;
  const int lane = t & 63;

  __shared__ float dec_lds[64];
  __shared__ float v_lds[64];
  __shared__ float score_lds[512];
  __shared__ float p_lds[512];
  __shared__ __align__(16) float cpart[8 * 512];           // 16 KB, also used
                                                           // as dec-reduce buf
  __shared__ __align__(16) unsigned short bfrag[2][4096];  // dbuf x 8KB

  // ---- decoder projection: dec[u] = sum_e dh[b,e]*w1[e,u] + w1b[u] + w2b[u]
  {
    const float* dhb = dh + (size_t)b * DD;
    const int e0 = wave * 32;
    float s = 0.f;
    #pragma unroll 8
    for (int i = 0; i < 32; ++i) {
      int e = e0 + i;
      s = fmaf(dhb[e], w1[e * UU + lane], s);   // dh broadcast, w1 coalesced
    }
    cpart[t] = s;
  }
  __syncthreads();
  if (t < 64) {
    float d = w1b[t] + w2b[t];
    #pragma unroll
    for (int q = 0; q < 16; ++q) d += cpart[q * 64 + t];
    dec_lds[t] = d;
    v_lds[t] = vk[t];
    // NOTE: v_bias intentionally omitted — softmax is exactly invariant to it.
  }
  // dec_lds/v_lds consumed only after the k-loop (many barriers in between).
  // cpart is re-written only after the score barrier, well past this read.

  // ---- projection GEMM over the whole S (single tile, no online softmax) --
  const int row0 = wave * 32;
  const float* aptr =
      x + ((size_t)b * SQ + row0 + (lane & 15)) * ED + ((lane >> 4) * 8);

  const f32x4 zero4 = {0.f, 0.f, 0.f, 0.f};
  f32x4 acc[2][4];   // [m-subtile][n-subtile]
  #pragma unroll
  for (int m = 0; m < 2; ++m)
    #pragma unroll
    for (int n = 0; n < 4; ++n) acc[m][n] = zero4;

  // stage k=0 fragments (reg-staged copy: global -> VGPR -> LDS, 8B/thread)
  {
    bf16x4 tmp = *(const bf16x4*)(wsb + t * 4);
    *(bf16x4*)&bfrag[0][t * 4] = tmp;
  }
  // A prefetch for k=0 (fp32, 8 floats per lane per m-subtile)
  float4 acur[2][2], anxt[2][2];
  #pragma unroll
  for (int m = 0; m < 2; ++m) {
    acur[m][0] = *(const float4*)(aptr + (size_t)(m * 16) * ED);
    acur[m][1] = *(const float4*)(aptr + (size_t)(m * 16) * ED + 4);
  }

  #pragma unroll 2
  for (int k = 0; k < 16; ++k) {
    __syncthreads();               // bfrag[k&1] staged; prev reads drained
    const int buf = k & 1;
    if (k < 15) {
      // stage k+1 into the other buffer + prefetch next A
      bf16x4 tmp = *(const bf16x4*)(wsb + (k + 1) * 4096 + t * 4);
      #pragma unroll
      for (int m = 0; m < 2; ++m) {
        anxt[m][0] = *(const float4*)(aptr + (size_t)(m * 16) * ED + (k + 1) * 32);
        anxt[m][1] = *(const float4*)(aptr + (size_t)(m * 16) * ED + (k + 1) * 32 + 4);
      }
      *(bf16x4*)&bfrag[buf ^ 1][t * 4] = tmp;
    }
    // B fragments from LDS (hi at offset 0, lo at offset 2048 ushorts)
    bf16x8 bhi[4], blo[4];
    #pragma unroll
    for (int n = 0; n < 4; ++n) {
      bhi[n] = *(const bf16x8*)&bfrag[buf][n * 512 + lane * 8];
      blo[n] = *(const bf16x8*)&bfrag[buf][2048 + n * 512 + lane * 8];
    }
    // split A to hi/lo bf16 and MFMA
    #pragma unroll
    for (int m = 0; m < 2; ++m) {
      float av[8] = {acur[m][0].x, acur[m][0].y, acur[m][0].z, acur[m][0].w,
                     acur[m][1].x, acur[m][1].y, acur[m][1].z, acur[m][1].w};
      bf16x8 ahi, alo;
      #pragma unroll
      for (int i = 0; i < 8; ++i) {
        unsigned short h = bf16_rne(av[i]);
        float hf = __uint_as_float((unsigned int)h << 16);
        unsigned short l = bf16_rne(av[i] - hf);
        ahi[i] = (short)h;
        alo[i] = (short)l;
      }
      #pragma unroll
      for (int n = 0; n < 4; ++n) {
        acc[m][n] = __builtin_amdgcn_mfma_f32_16x16x32_bf16(ahi, bhi[n], acc[m][n], 0, 0, 0);
        acc[m][n] = __builtin_amdgcn_mfma_f32_16x16x32_bf16(ahi, blo[n], acc[m][n], 0, 0, 0);
        acc[m][n] = __builtin_amdgcn_mfma_f32_16x16x32_bf16(alo, bhi[n], acc[m][n], 0, 0, 0);
      }
    }
    #pragma unroll
    for (int m = 0; m < 2; ++m) {
      acur[m][0] = anxt[m][0];
      acur[m][1] = anxt[m][1];
    }
  }

  // ---- scores: score[s] = sum_u tanh(enc[s,u] + dec[u]) * v[u] -------------
  // C/D layout (verified m89/m91): col u = lane&15 (+16*nt), row = (lane>>4)*4+reg
  {
    const int ul = lane & 15;
    const int rg = lane >> 4;
    #pragma unroll
    for (int m = 0; m < 2; ++m) {
      #pragma unroll
      for (int r = 0; r < 4; ++r) {
        float part = 0.f;
        #pragma unroll
        for (int n = 0; n < 4; ++n) {
          int u = n * 16 + ul;
          float z = acc[m][n][r] + dec_lds[u];
          float ez = __expf(2.f * z);              // tanh(z) = 1 - 2/(e^2z+1)
          float th = 1.f - 2.f / (ez + 1.f);
          part = fmaf(th, v_lds[u], part);
        }
        part += __shfl_xor(part, 1);
        part += __shfl_xor(part, 2);
        part += __shfl_xor(part, 4);
        part += __shfl_xor(part, 8);               // sum over the 16 u-lanes
        if (ul == 0) score_lds[row0 + m * 16 + rg * 4 + r] = part;
      }
    }
  }
  __syncthreads();

  // ---- softmax over S (replicated per thread; deterministic & identical) --
  if (t < 512) {
    float mx = -1e30f;
    for (int i = 0; i < 512; i += 4) {
      float4 s4 = *(const float4*)&score_lds[i];
      mx = fmaxf(mx, fmaxf(fmaxf(s4.x, s4.y), fmaxf(s4.z, s4.w)));
    }
    p_lds[t] = __expf(score_lds[t] - mx);
  }
  __syncthreads();

  // ---- context: c[e] = sum_s p[s] * x[b,s,e] ------------------------------
  // 8 s-subsets x 128 e-chunks; thread handles 4 consecutive e via float4,
  // 64 independent 16B loads (L2/L3-resident row) -> deep MLP per thread.
  {
    const int subset = t >> 7;          // 0..7
    const int ec = t & 127;             // e-chunk: e = ec*4 .. ec*4+3
    const float* xc = x + (size_t)b * SQ * ED + ec * 4;
    f32x4 c = zero4;
    #pragma unroll 8
    for (int i = 0; i < 64; ++i) {
      int s = subset + i * 8;
      float4 v = *(const float4*)(xc + (size_t)s * ED);
      float p = p_lds[s];
      c[0] = fmaf(p, v.x, c[0]);
      c[1] = fmaf(p, v.y, c[1]);
      c[2] = fmaf(p, v.z, c[2]);
      c[3] = fmaf(p, v.w, c[3]);
    }
    *(f32x4*)&cpart[subset * 512 + ec * 4] = c;
  }
  __syncthreads();

  if (t < 512) {
    // softmax denominator (replicated over the 512 writer threads)
    float l = 0.f;
    for (int i = 0; i < 512; i += 4) {
      float4 p4 = *(const float4*)&p_lds[i];
      l += p4.x + p4.y + p4.z + p4.w;
    }
    const float inv_l = 1.f / l;
    float csum = 0.f;
    #pragma unroll
    for (int ss = 0; ss < 8; ++ss) csum += cpart[ss * 512 + t];
    out[(size_t)b * ED + t] = csum * inv_l;                       // context
    out[(size_t)NB * ED + (size_t)b * SQ + t] = p_lds[t] * inv_l; // att_w
  }
}

// ---------------------------------------------------------------------------
extern "C" void kernel_launch(void* const* d_in, const int* in_sizes, int n_in,
                              void* d_out, int out_size, void* d_ws, size_t ws_size,
                              hipStream_t stream) {
  const float* dh  = (const float*)d_in[0];  // decoder_hidden_state
  const float* x   = (const float*)d_in[1];  // encoder_output
  const float* w1  = (const float*)d_in[2];  // w1_kernel
  const float* w1b = (const float*)d_in[3];  // w1_bias
  const float* w2  = (const float*)d_in[4];  // w2_kernel
  const float* w2b = (const float*)d_in[5];  // w2_bias
  const float* vk  = (const float*)d_in[6];  // v_kernel
  // d_in[7] = v_bias: softmax is exactly invariant to it -> unused.
  unsigned short* wsb = (unsigned short*)d_ws;  // 131072 bytes used
  float* out = (float*)d_out;

  prep_w2_frags<<<256, 256, 0, stream>>>(w2, wsb);
  attn_fused<<<NB, 1024, 0, stream>>>(dh, x, w1, w1b, w2b, vk, wsb, out);
}

// Round 3
// 98.762 us; speedup vs baseline: 1.1904x; 1.1904x over previous
//
#include <hip/hip_runtime.h>
#include <hip/hip_bf16.h>

// Problem constants (fixed by the reference):
constexpr int NB = 256;   // batch
constexpr int SQ = 512;   // sequence length
constexpr int ED = 512;   // encoder dim
constexpr int DD = 512;   // decoder dim
constexpr int UU = 64;    // attention units
constexpr int NT = 4;     // s-tiles per batch
constexpr int TS = 128;   // rows per tile

typedef __attribute__((ext_vector_type(8))) short bf16x8;
typedef __attribute__((ext_vector_type(4))) float f32x4;

__device__ __forceinline__ unsigned short bf16_rne(float f) {
  unsigned int u = __float_as_uint(f);
  u += 0x7FFFu + ((u >> 16) & 1u);
  return (unsigned short)(u >> 16);
}

// ws layout (bytes):
//   [0,       131072) : w2 hi/lo bf16 fragments
//   [131072,  196608) : dec[256][64]  (w1 proj + both biases folded)
//   [196608,  200704) : mbuf[256][4]  tile max
//   [200704,  204800) : lbuf[256][4]  tile exp-sum
//   [204800, 2301952) : ctile[256][4][512] partial contexts
constexpr size_t WS_DEC   = 131072;
constexpr size_t WS_MBUF  = 196608;
constexpr size_t WS_LBUF  = 200704;
constexpr size_t WS_CTILE = 204800;

// ---------------------------------------------------------------------------
// Kernel P1: split w2 (512x64 fp32) into hi/lo bf16, pre-arranged in MFMA
// B-fragment order for mfma_f32_16x16x32_bf16 (B[k][col]: lane l holds
// k=(l>>4)*8+j, col=l&15). Per k-step an 8192-byte contiguous block.
// ---------------------------------------------------------------------------
__global__ void prep_w2_frags(const float* __restrict__ w2,
                              unsigned short* __restrict__ wsb) {
  int tid = blockIdx.x * 256 + threadIdx.x;   // 0..65535
  int j    = tid & 7;
  int lane = (tid >> 3) & 63;
  int nt   = (tid >> 9) & 3;
  int hl   = (tid >> 11) & 1;
  int ks   = tid >> 12;
  int e = ks * 32 + (lane >> 4) * 8 + j;
  int u = nt * 16 + (lane & 15);
  float v = w2[e * UU + u];
  unsigned short hi = bf16_rne(v);
  unsigned short o;
  if (hl == 0) {
    o = hi;
  } else {
    float hif = __uint_as_float((unsigned int)hi << 16);
    o = bf16_rne(v - hif);   // residual, next ~8 mantissa bits
  }
  wsb[tid] = o;
}

// ---------------------------------------------------------------------------
// Kernel P2: dec[b,u] = sum_e dh[b,e]*w1[e,u] + w1b[u] + w2b[u]
// ---------------------------------------------------------------------------
__global__ __launch_bounds__(256) void dec_proj(
    const float* __restrict__ dh, const float* __restrict__ w1,
    const float* __restrict__ w1b, const float* __restrict__ w2b,
    float* __restrict__ dec_ws) {
  const int b = blockIdx.x;
  const int t = threadIdx.x;
  const int wave = t >> 6;
  const int lane = t & 63;
  __shared__ float red[256];
  const float* dhb = dh + (size_t)b * DD;
  const int e0 = wave * 128;
  float s = 0.f;
  #pragma unroll 8
  for (int i = 0; i < 128; ++i) {
    int e = e0 + i;
    s = fmaf(dhb[e], w1[e * UU + lane], s);   // dh broadcast, w1 coalesced
  }
  red[t] = s;
  __syncthreads();
  if (t < 64) {
    float d = w1b[t] + w2b[t] + red[t] + red[64 + t] + red[128 + t] + red[192 + t];
    dec_ws[b * UU + t] = d;
  }
}

// ---------------------------------------------------------------------------
// Kernel A: per (b, s-tile of 128 rows). 256 threads = 4 waves; wave w owns
// rows [tile*128 + w*32, +32). Proj GEMM via split-bf16 MFMA, tile-local
// softmax (m,l), unnormalized p -> out att region, partial context -> ctile.
// 4 independent blocks/CU so barrier-drain stalls of one block overlap
// compute of another (round-2 failure mode: 1 lockstep block/CU).
// ---------------------------------------------------------------------------
__global__ __launch_bounds__(256, 4) void attn_tile(
    const float* __restrict__ x,     // [256,512,512]
    const float* __restrict__ vk,    // [64]
    const unsigned short* __restrict__ wsb,
    const float* __restrict__ dec_ws,
    float* __restrict__ mbuf, float* __restrict__ lbuf,
    float* __restrict__ ctile,
    float* __restrict__ out)
{
  const int b    = blockIdx.x >> 2;
  const int tile = blockIdx.x & 3;
  const int t = threadIdx.x;
  const int wave = t >> 6;
  const int lane = t & 63;

  __shared__ float dec_lds[64];
  __shared__ float v_lds[64];
  __shared__ float score_lds[TS];
  __shared__ float p_lds[TS];
  __shared__ __align__(16) float cpart[2 * 512];
  __shared__ __align__(16) unsigned short bfrag[2][4096];  // dbuf x 8KB

  if (t < 64) {
    dec_lds[t] = dec_ws[b * UU + t];
    v_lds[t] = vk[t];
  }

  // ---- projection GEMM over this tile's 128 rows --------------------------
  const int row0 = tile * TS + wave * 32;
  const float* aptr =
      x + ((size_t)b * SQ + row0 + (lane & 15)) * ED + ((lane >> 4) * 8);

  const f32x4 zero4 = {0.f, 0.f, 0.f, 0.f};
  f32x4 acc[2][4];
  #pragma unroll
  for (int m = 0; m < 2; ++m)
    #pragma unroll
    for (int n = 0; n < 4; ++n) acc[m][n] = zero4;

  // stage k=0 fragments (32 B per thread)
  {
    bf16x8 t0 = *(const bf16x8*)(wsb + t * 16);
    bf16x8 t1 = *(const bf16x8*)(wsb + t * 16 + 8);
    *(bf16x8*)&bfrag[0][t * 16] = t0;
    *(bf16x8*)&bfrag[0][t * 16 + 8] = t1;
  }
  float4 acur[2][2], anxt[2][2];
  #pragma unroll
  for (int m = 0; m < 2; ++m) {
    acur[m][0] = *(const float4*)(aptr + (size_t)(m * 16) * ED);
    acur[m][1] = *(const float4*)(aptr + (size_t)(m * 16) * ED + 4);
  }

  #pragma unroll 2
  for (int k = 0; k < 16; ++k) {
    __syncthreads();
    const int buf = k & 1;
    if (k < 15) {
      bf16x8 t0 = *(const bf16x8*)(wsb + (k + 1) * 4096 + t * 16);
      bf16x8 t1 = *(const bf16x8*)(wsb + (k + 1) * 4096 + t * 16 + 8);
      #pragma unroll
      for (int m = 0; m < 2; ++m) {
        anxt[m][0] = *(const float4*)(aptr + (size_t)(m * 16) * ED + (k + 1) * 32);
        anxt[m][1] = *(const float4*)(aptr + (size_t)(m * 16) * ED + (k + 1) * 32 + 4);
      }
      *(bf16x8*)&bfrag[buf ^ 1][t * 16] = t0;
      *(bf16x8*)&bfrag[buf ^ 1][t * 16 + 8] = t1;
    }
    bf16x8 bhi[4], blo[4];
    #pragma unroll
    for (int n = 0; n < 4; ++n) {
      bhi[n] = *(const bf16x8*)&bfrag[buf][n * 512 + lane * 8];
      blo[n] = *(const bf16x8*)&bfrag[buf][2048 + n * 512 + lane * 8];
    }
    #pragma unroll
    for (int m = 0; m < 2; ++m) {
      float av[8] = {acur[m][0].x, acur[m][0].y, acur[m][0].z, acur[m][0].w,
                     acur[m][1].x, acur[m][1].y, acur[m][1].z, acur[m][1].w};
      bf16x8 ahi, alo;
      #pragma unroll
      for (int i = 0; i < 8; ++i) {
        unsigned short h = bf16_rne(av[i]);
        float hf = __uint_as_float((unsigned int)h << 16);
        unsigned short l = bf16_rne(av[i] - hf);
        ahi[i] = (short)h;
        alo[i] = (short)l;
      }
      #pragma unroll
      for (int n = 0; n < 4; ++n) {
        acc[m][n] = __builtin_amdgcn_mfma_f32_16x16x32_bf16(ahi, bhi[n], acc[m][n], 0, 0, 0);
        acc[m][n] = __builtin_amdgcn_mfma_f32_16x16x32_bf16(ahi, blo[n], acc[m][n], 0, 0, 0);
        acc[m][n] = __builtin_amdgcn_mfma_f32_16x16x32_bf16(alo, bhi[n], acc[m][n], 0, 0, 0);
      }
    }
    #pragma unroll
    for (int m = 0; m < 2; ++m) {
      acur[m][0] = anxt[m][0];
      acur[m][1] = anxt[m][1];
    }
  }

  // ---- scores: score[s] = sum_u tanh(enc + dec) * v ------------------------
  {
    const int ul = lane & 15;
    const int rg = lane >> 4;
    #pragma unroll
    for (int m = 0; m < 2; ++m) {
      #pragma unroll
      for (int r = 0; r < 4; ++r) {
        float part = 0.f;
        #pragma unroll
        for (int n = 0; n < 4; ++n) {
          int u = n * 16 + ul;
          float z = acc[m][n][r] + dec_lds[u];
          float ez = __expf(2.f * z);              // tanh via exp
          float th = 1.f - 2.f / (ez + 1.f);
          part = fmaf(th, v_lds[u], part);
        }
        part += __shfl_xor(part, 1);
        part += __shfl_xor(part, 2);
        part += __shfl_xor(part, 4);
        part += __shfl_xor(part, 8);
        if (ul == 0) score_lds[wave * 32 + m * 16 + rg * 4 + r] = part;
      }
    }
  }
  __syncthreads();

  // ---- tile-local softmax pieces ------------------------------------------
  float mx = -1e30f;
  #pragma unroll
  for (int i = 0; i < TS; i += 4) {
    float4 s4 = *(const float4*)&score_lds[i];
    mx = fmaxf(mx, fmaxf(fmaxf(s4.x, s4.y), fmaxf(s4.z, s4.w)));
  }
  if (t < TS) {
    float p = __expf(score_lds[t] - mx);
    p_lds[t] = p;
    // unnormalized p into the att output region; combine() rescales in place
    out[(size_t)NB * ED + (size_t)b * SQ + tile * TS + t] = p;
  }
  __syncthreads();
  if (t < 64) {
    float v = p_lds[t] + p_lds[t + 64];
    v += __shfl_xor(v, 1);  v += __shfl_xor(v, 2);
    v += __shfl_xor(v, 4);  v += __shfl_xor(v, 8);
    v += __shfl_xor(v, 16); v += __shfl_xor(v, 32);
    if (t == 0) {
      mbuf[b * NT + tile] = mx;
      lbuf[b * NT + tile] = v;
    }
  }

  // ---- partial context: ctile[e] = sum_{s in tile} p[s] x[b,s,e] ----------
  {
    const int subset = t >> 7;          // 0..1
    const int ec = t & 127;             // float4 e-chunk
    const float* xc = x + ((size_t)b * SQ + tile * TS) * ED + ec * 4;
    f32x4 c = zero4;
    #pragma unroll 8
    for (int i = 0; i < 64; ++i) {
      int s = subset + i * 2;
      float4 v = *(const float4*)(xc + (size_t)s * ED);
      float p = p_lds[s];
      c[0] = fmaf(p, v.x, c[0]);
      c[1] = fmaf(p, v.y, c[1]);
      c[2] = fmaf(p, v.z, c[2]);
      c[3] = fmaf(p, v.w, c[3]);
    }
    *(f32x4*)&cpart[subset * 512 + ec * 4] = c;
  }
  __syncthreads();
  #pragma unroll
  for (int e = t; e < 512; e += 256) {
    ctile[((size_t)b * NT + tile) * ED + e] = cpart[e] + cpart[512 + e];
  }
}

// ---------------------------------------------------------------------------
// Kernel B: combine tiles. M = max m_t; L = sum l_t e^{m_t-M};
// att *= e^{m_tile-M}/L (in place); ctx = sum_t ctile_t e^{m_t-M}/L.
// ---------------------------------------------------------------------------
__global__ __launch_bounds__(256) void combine(
    const float* __restrict__ mbuf, const float* __restrict__ lbuf,
    const float* __restrict__ ctile, float* __restrict__ out) {
  const int b = blockIdx.x;
  const int t = threadIdx.x;
  float m0 = mbuf[b * NT + 0], m1 = mbuf[b * NT + 1];
  float m2 = mbuf[b * NT + 2], m3 = mbuf[b * NT + 3];
  float M = fmaxf(fmaxf(m0, m1), fmaxf(m2, m3));
  float e0 = __expf(m0 - M), e1 = __expf(m1 - M);
  float e2 = __expf(m2 - M), e3 = __expf(m3 - M);
  float L = lbuf[b * NT + 0] * e0 + lbuf[b * NT + 1] * e1 +
            lbuf[b * NT + 2] * e2 + lbuf[b * NT + 3] * e3;
  float inv = 1.f / L;
  float sc[NT] = {e0 * inv, e1 * inv, e2 * inv, e3 * inv};

  float* att = out + (size_t)NB * ED + (size_t)b * SQ;
  #pragma unroll
  for (int s = t; s < SQ; s += 256) att[s] *= sc[s >> 7];

  const float* ct = ctile + (size_t)b * NT * ED;
  #pragma unroll
  for (int e = t; e < ED; e += 256) {
    float c = ct[e] * sc[0] + ct[ED + e] * sc[1] +
              ct[2 * ED + e] * sc[2] + ct[3 * ED + e] * sc[3];
    out[(size_t)b * ED + e] = c;
  }
}

// ---------------------------------------------------------------------------
extern "C" void kernel_launch(void* const* d_in, const int* in_sizes, int n_in,
                              void* d_out, int out_size, void* d_ws, size_t ws_size,
                              hipStream_t stream) {
  const float* dh  = (const float*)d_in[0];
  const float* x   = (const float*)d_in[1];
  const float* w1  = (const float*)d_in[2];
  const float* w1b = (const float*)d_in[3];
  const float* w2  = (const float*)d_in[4];
  const float* w2b = (const float*)d_in[5];
  const float* vk  = (const float*)d_in[6];
  // d_in[7] = v_bias: softmax exactly invariant -> unused.
  unsigned short* wsb = (unsigned short*)d_ws;
  float* dec_ws = (float*)((char*)d_ws + WS_DEC);
  float* mbuf   = (float*)((char*)d_ws + WS_MBUF);
  float* lbuf   = (float*)((char*)d_ws + WS_LBUF);
  float* ctile  = (float*)((char*)d_ws + WS_CTILE);
  float* out = (float*)d_out;

  prep_w2_frags<<<256, 256, 0, stream>>>(w2, wsb);
  dec_proj<<<NB, 256, 0, stream>>>(dh, w1, w1b, w2b, dec_ws);
  attn_tile<<<NB * NT, 256, 0, stream>>>(x, vk, wsb, dec_ws, mbuf, lbuf, ctile, out);
  combine<<<NB, 256, 0, stream>>>(mbuf, lbuf, ctile, out);
}